// Round 10
// baseline (262.588 us; speedup 1.0000x reference)
//
#include <hip/hip_runtime.h>
#include <hip/hip_bf16.h>
#include <stdint.h>

// TT linear 4096->4096, B=2048, ranks (1,16,16,16,1), modes 8^4.
// R18: A-from-global. R14's invariant 2770cy/iter = MFMA(1242) +
// LDS-unit(~1530: 128 ds_read_b128 + 48KB DMA writes) with ~no overlap;
// every schedule variant (R11-R17) kept the LDS bill constant and landed
// 74-87us. Fix: A fragments load global->VGPR directly (per-lane addr =
// exact MFMA operand layout; one 128B line per A-row covers the whole
// K-step -> L1/L2-served, 4x wave reuse). LDS holds only B: reads halve
// (64 b128/CU-iter), DMA writes 32KB/iter, LDS 3x32KB=96KB.
// A double-banked in regs (afA/afB, static idx), prefetched 1 tile ahead.
// vmcnt ledger: 12 issues/iter (4 B-DMA + 8 A-loads); mid-iter vmcnt(12)
// drains prev iter's ops (A(kt) valid, B(kt+1) landed) — order-agnostic.
// Boundary {lgkmcnt(0); s_barrier} guards buf[cur] recycle (R11 invariant).
// Tile 128x256, BK=64, 512 thr (8 waves 2Mx4N, 64x64/wave), grid 256,
// quadrant XCD map (FETCH 65MB), prep0/build_w = R1 verbatim.

typedef __bf16 bf16_t;
typedef __bf16 bf16x8 __attribute__((ext_vector_type(8)));
typedef __bf16 bf16x4 __attribute__((ext_vector_type(4)));
typedef float floatx4 __attribute__((ext_vector_type(4)));

#define BATCH_N 2048
#define KD 4096
#define ND 4096

__device__ static inline void load_lds16(const void* g, void* l) {
    __builtin_amdgcn_global_load_lds(
        (const __attribute__((address_space(1))) void*)g,
        (__attribute__((address_space(3))) void*)l, 16, 0, 0);
}

// ---- prep0: blocks [0,4096) cvt x fp32->bf16; blocks [4096,4160) build
//      P[n01][m01][r2]; blocks [4160,4224) build T[m23][n23][r2] --------
__global__ __launch_bounds__(256) void prep0(const float* __restrict__ x,
                                             const float* __restrict__ c0,
                                             const float* __restrict__ c1,
                                             const float* __restrict__ c2,
                                             const float* __restrict__ c3,
                                             bf16_t* __restrict__ xb,
                                             float* __restrict__ Pg,
                                             float* __restrict__ Tg) {
    const int t = threadIdx.x;
    const int b = blockIdx.x;

    if (b < 4096) {                     // ---- cvt_x ----
        int g = b * 256 + t;
        const float4* xv = (const float4*)x;
        float4 a = xv[g * 2];
        float4 c = xv[g * 2 + 1];
        bf16x8 o;
        o[0] = (bf16_t)a.x; o[1] = (bf16_t)a.y; o[2] = (bf16_t)a.z; o[3] = (bf16_t)a.w;
        o[4] = (bf16_t)c.x; o[5] = (bf16_t)c.y; o[6] = (bf16_t)c.z; o[7] = (bf16_t)c.w;
        ((bf16x8*)xb)[g] = o;
        return;
    }

    __shared__ float s0[128];
    __shared__ float s1[2048];

    if (b < 4160) {                     // ---- P[n01][m01][r2] ----
        const int n01 = b - 4096, n0 = n01 >> 3, n1 = n01 & 7;
        if (t < 128) s0[t] = c0[(t >> 4) * 128 + n0 * 16 + (t & 15)];   // [m0][r1]
        for (int i = t; i < 2048; i += 256) {                            // [r1][m1][r2]
            int r1 = i >> 7, m1 = (i >> 4) & 7, r2 = i & 15;
            s1[i] = c1[(r1 * 8 + m1) * 128 + n1 * 16 + r2];
        }
        __syncthreads();
#pragma unroll
        for (int j = 0; j < 4; ++j) {
            int o = j * 256 + t, m01 = o >> 4, r2 = o & 15;
            int m0 = m01 >> 3, m1 = m01 & 7;
            float s = 0.f;
#pragma unroll
            for (int r1 = 0; r1 < 16; ++r1)
                s += s0[m0 * 16 + r1] * s1[r1 * 128 + m1 * 16 + r2];
            Pg[n01 * 1024 + o] = s;
        }
        return;
    }

    {                                   // ---- T[m23][n23][r2] ----
        const int m23 = b - 4160, m2 = m23 >> 3, m3 = m23 & 7;
        if (t < 128) s0[t] = c3[((t >> 3) * 8 + m3) * 8 + (t & 7)];     // [r3][n3]
        for (int i = t; i < 2048; i += 256) {                            // [r2][n2][r3]
            int r2 = i >> 7, n2 = (i >> 4) & 7, r3 = i & 15;
            s1[i] = c2[(r2 * 8 + m2) * 128 + n2 * 16 + r3];
        }
        __syncthreads();
#pragma unroll
        for (int j = 0; j < 4; ++j) {
            int o = j * 256 + t, n23 = o >> 4, r2 = o & 15;
            int n2 = n23 >> 3, n3 = n23 & 7;
            float s = 0.f;
#pragma unroll
            for (int r3 = 0; r3 < 16; ++r3)
                s += s1[r2 * 128 + n2 * 16 + r3] * s0[r3 * 8 + n3];
            Tg[m23 * 1024 + o] = s;
        }
    }
}

// ---- build_w: 256 blocks = (q in [0,4)) x (n01 in [0,64)). (R1 verbatim)
__global__ __launch_bounds__(256) void build_w(const float* __restrict__ Pg,
                                               const float* __restrict__ Tg,
                                               bf16_t* __restrict__ W) {
    const int t = threadIdx.x;
    const int b = blockIdx.x;
    const int n01 = b & 63, q = b >> 6;
    const int cg = t & 15;
    const int mr = t >> 4;
    const float* Pb = Pg + n01 * 1024 + q * 256;   // Pb[ml*16 + r2], uniform

#pragma unroll 1
    for (int ms = 0; ms < 4; ++ms) {
        const int m23 = ms * 16 + mr;
        float Tr[4][16];
#pragma unroll
        for (int jj = 0; jj < 4; ++jj) {
            const float4* tp = (const float4*)(Tg + (m23 * 64 + cg * 4 + jj) * 16);
#pragma unroll
            for (int w = 0; w < 4; ++w) {
                float4 v = tp[w];
                Tr[jj][w * 4 + 0] = v.x;
                Tr[jj][w * 4 + 1] = v.y;
                Tr[jj][w * 4 + 2] = v.z;
                Tr[jj][w * 4 + 3] = v.w;
            }
        }
#pragma unroll 4
        for (int ml = 0; ml < 16; ++ml) {
            float a0 = 0.f, a1 = 0.f, a2 = 0.f, a3 = 0.f;
#pragma unroll
            for (int r2 = 0; r2 < 16; ++r2) {
                float p = Pb[ml * 16 + r2];     // wave-uniform -> SGPR
                a0 += p * Tr[0][r2];
                a1 += p * Tr[1][r2];
                a2 += p * Tr[2][r2];
                a3 += p * Tr[3][r2];
            }
            bf16x4 o;
            o[0] = (bf16_t)a0; o[1] = (bf16_t)a1; o[2] = (bf16_t)a2; o[3] = (bf16_t)a3;
            *(bf16x4*)(W + (size_t)((q * 16 + ml) * 64 + m23) * 4096 + n01 * 64 + cg * 4) = o;
        }
    }
}

// ---- BT GEMM R18: C[m,n] = sum_k A[m,k]*B[n,k] + bias[n] ---------------
// A: global->reg (double-banked, 1 tile ahead). B: LDS triple buffer.
__global__ __launch_bounds__(512, 2) void gemm_bt6(const bf16_t* __restrict__ A,
                                                   const bf16_t* __restrict__ B,
                                                   const float* __restrict__ bias,
                                                   float* __restrict__ C) {
    __shared__ bf16_t smem[3][16384];   // B only: 3 x 32 KB
    const int t = threadIdx.x;
    const int bid = blockIdx.x;
    // Quadrant XCD mapping (R14-verified): XCD x owns bm in [(x&1)*8,+8)
    // x bn in [(x>>1)*4,+4). Bijective over 256 blocks.
    const int xcd = bid & 7, gi = bid >> 3;       // gi in [0,32)
    const int bm = (xcd & 1) * 8 + (gi & 7);      // [0,16)
    const int bn = (xcd >> 1) * 4 + (gi >> 3);    // [0,16)
    const int lane = t & 63, wave = t >> 6;
    const int wm = wave >> 2, wn = wave & 3;

    // B staging source (R8 swizzle): srow=t>>3 in [0,64), chunk=(t&7)^(srow&7)
    const int srow = t >> 3;
    const int lc = (t & 7) ^ (srow & 7);
    const bf16_t* Bg = B + (size_t)(bn * 256 + srow) * KD + lc * 8;
    const int woff = wave * 512;                  // elems, wave-uniform

    const int fr = lane & 15;
    const int fc = lane >> 4;
    // A per-lane operand pointer: row = bm*128 + wm*64 + (im*16) + fr,
    // k = kt*64 + kk*32 + fc*8  (exact 16x16x32 A-operand layout).
    const bf16_t* Aptr = A + (size_t)(bm * 128 + wm * 64 + fr) * KD + fc * 8;

    floatx4 acc[4][4];
    floatx4 zero = {0.f, 0.f, 0.f, 0.f};
#pragma unroll
    for (int i2 = 0; i2 < 4; ++i2)
#pragma unroll
        for (int j = 0; j < 4; ++j) acc[i2][j] = zero;

    bf16x8 afA[8], afB[8];              // [im*2+kk], static-indexed banks

#define LOADA(bank, kt)                                                        \
    {                                                                          \
        _Pragma("unroll")                                                      \
        for (int im = 0; im < 4; ++im) {                                       \
            _Pragma("unroll")                                                  \
            for (int kk = 0; kk < 2; ++kk)                                     \
                bank[im * 2 + kk] = *(const bf16x8*)(                          \
                    Aptr + (size_t)(im * 16) * KD + (kt) * 64 + kk * 32);      \
        }                                                                      \
    }

#define STAGEB(kt, buf)                                                        \
    {                                                                          \
        bf16_t* bb = &smem[buf][0];                                            \
        const size_t ko = (size_t)(kt) * 64;                                   \
        _Pragma("unroll")                                                      \
        for (int c = 0; c < 4; ++c)                                            \
            load_lds16(Bg + (size_t)c * 64 * KD + ko, bb + c * 4096 + woff);   \
    }

#define COMPUTE(bank, cur)                                                     \
    {                                                                          \
        const bf16_t* Bb = &smem[cur][0];                                      \
        _Pragma("unroll")                                                      \
        for (int kk = 0; kk < 2; ++kk) {                                       \
            const int pA = (fc + kk * 4) ^ (fr & 7);                           \
            bf16x8 bf[4];                                                      \
            _Pragma("unroll")                                                  \
            for (int in = 0; in < 4; ++in)                                     \
                bf[in] = *(const bf16x8*)(Bb + (wn * 64 + in * 16 + fr) * 64 + \
                                          pA * 8);                             \
            __builtin_amdgcn_s_setprio(1);                                     \
            _Pragma("unroll")                                                  \
            for (int im = 0; im < 4; ++im) {                                   \
                _Pragma("unroll")                                              \
                for (int in = 0; in < 4; ++in)                                 \
                    acc[im][in] = __builtin_amdgcn_mfma_f32_16x16x32_bf16(     \
                        bank[im * 2 + kk], bf[in], acc[im][in], 0, 0, 0);      \
            }                                                                  \
            __builtin_amdgcn_s_setprio(0);                                     \
        }                                                                      \
    }

    // ---- prologue: B(0)->buf0, B(1)->buf1, A(0)->afA; full drain once ----
    STAGEB(0, 0);
    STAGEB(1, 1);
    LOADA(afA, 0);
    asm volatile("s_waitcnt vmcnt(0)\n\ts_barrier" ::: "memory");

    int cur = 0;
#pragma unroll 1
    for (int j = 0; j < 32; ++j) {
        const int kt0 = 2 * j;
        // ---- even sub-iter: compute afA/buf[cur]; prefetch A(kt0+1), B(kt0+2)
        {
            if (kt0 < 62) {
                int nb = cur + 2; if (nb >= 3) nb -= 3;
                STAGEB(kt0 + 2, nb);
            }
            LOADA(afB, kt0 + 1);        // kt0 <= 62 always here
            if (j < 31) {
                asm volatile("s_waitcnt vmcnt(12)" ::: "memory");
            } else {
                asm volatile("s_waitcnt vmcnt(8)" ::: "memory");
            }
            COMPUTE(afA, cur);
            asm volatile("s_waitcnt lgkmcnt(0)\n\ts_barrier" ::: "memory");
            cur = (cur == 2) ? 0 : cur + 1;
        }
        // ---- odd sub-iter: compute afB/buf[cur]; prefetch A(kt0+2), B(kt0+3)
        {
            const int kt1 = kt0 + 1;
            if (kt1 < 62) {
                int nb = cur + 2; if (nb >= 3) nb -= 3;
                STAGEB(kt1 + 2, nb);
            }
            if (kt1 < 63) LOADA(afA, kt1 + 1);
            if (j < 31) {
                asm volatile("s_waitcnt vmcnt(12)" ::: "memory");
            } else {
                asm volatile("s_waitcnt vmcnt(0)" ::: "memory");
            }
            COMPUTE(afB, cur);
            asm volatile("s_waitcnt lgkmcnt(0)\n\ts_barrier" ::: "memory");
            cur = (cur == 2) ? 0 : cur + 1;
        }
    }
#undef LOADA
#undef STAGEB
#undef COMPUTE

    // epilogue: D[m = (lane>>4)*4 + r][n = lane&15] per 16x16 frag
    const int rl = lane >> 4, cl = lane & 15;
    const size_t rbase = (size_t)bm * 128 + wm * 64;
    const int cbase = bn * 256 + wn * 64;
#pragma unroll
    for (int im = 0; im < 4; ++im) {
#pragma unroll
        for (int in = 0; in < 4; ++in) {
            int col = cbase + in * 16 + cl;
            float bv = bias[col];
#pragma unroll
            for (int r = 0; r < 4; ++r) {
                size_t row = rbase + im * 16 + rl * 4 + r;
                C[row * ND + col] = acc[im][in][r] + bv;
            }
        }
    }
}

extern "C" void kernel_launch(void* const* d_in, const int* in_sizes, int n_in,
                              void* d_out, int out_size, void* d_ws, size_t ws_size,
                              hipStream_t stream) {
    const float* x  = (const float*)d_in[0];
    const float* c0 = (const float*)d_in[1];
    const float* c1 = (const float*)d_in[2];
    const float* c2 = (const float*)d_in[3];
    const float* c3 = (const float*)d_in[4];
    const float* bias = (const float*)d_in[5];
    float* out = (float*)d_out;

    char* ws = (char*)d_ws;
    bf16_t* Xb = (bf16_t*)ws;                 // 16 MiB
    bf16_t* W  = (bf16_t*)(ws + (16u << 20)); // 32 MiB

    // P/T factor tables (512 KB) live at the front of d_out: written by
    // prep0, read by build_w, fully overwritten by gemm_bt6 afterwards.
    float* Pg = (float*)d_out;                // 64*64*16 fp32 = 256 KB
    float* Tg = Pg + 64 * 1024;               // 64*64*16 fp32 = 256 KB

    prep0<<<4224, 256, 0, stream>>>(x, c0, c1, c2, c3, Xb, Pg, Tg);
    build_w<<<256, 256, 0, stream>>>(Pg, Tg, W);
    gemm_bt6<<<256, 512, 0, stream>>>(Xb, W, bias, out);
}

// Round 11
// 170.724 us; speedup vs baseline: 1.5381x; 1.5381x over previous
//
#include <hip/hip_runtime.h>
#include <hip/hip_bf16.h>
#include <stdint.h>

// TT linear 4096->4096, B=2048, ranks (1,16,16,16,1), modes 8^4.
// R19 = R14 restored (measured best: gemm 73.8us, total 172.8us).
// Session ledger (gemm dispatch us): R8 80.8 | R11 74.2 | R12 4-phase
// 79.1 | R13 32x32 83.1 | R14 73.8 | R15 2blk/CU 86.9 | R16 64x128 83.1
// | R17 stagger 78.8 | R18 A-from-global 163.4. Eight structural
// variants bracket R14 from every direction; its iter time is the
// MFMA floor (1241cy) + LDS-unit floor (~1530cy) serialized, and every
// de-serialization attempt paid more elsewhere (sync, conflicts,
// latency cover, or VMEM request rate). Structure:
//  - 128x256 tile, BK=64, 512 thr (8 waves 2Mx4N, per-wave 64x64 =
//    4x4 frags of 16x16x32 MFMA), grid 256 = 1 block/CU.
//  - Triple-buffered LDS 3x48KB; counted boundary {vmcnt(6) lgkmcnt(0);
//    s_barrier}: the 6 next-next-tile DMA loads stay in flight across
//    the barrier; lgkm drain guards buf recycle vs global_load_lds.
//  - R8 XOR-swizzle staging (16B-chunk ^ row&7 on the global source,
//    LDS lane-linear): SQ_LDS_BANK_CONFLICT == 0 measured.
//  - Quadrant XCD map: XCD owns 8bm x 4bn -> FETCH 139->65.6MB.
// prep0/build_w = R1 verbatim (harness-verified).

typedef __bf16 bf16_t;
typedef __bf16 bf16x8 __attribute__((ext_vector_type(8)));
typedef __bf16 bf16x4 __attribute__((ext_vector_type(4)));
typedef float floatx4 __attribute__((ext_vector_type(4)));

#define BATCH_N 2048
#define KD 4096
#define ND 4096

__device__ static inline void load_lds16(const void* g, void* l) {
    __builtin_amdgcn_global_load_lds(
        (const __attribute__((address_space(1))) void*)g,
        (__attribute__((address_space(3))) void*)l, 16, 0, 0);
}

// ---- prep0: blocks [0,4096) cvt x fp32->bf16; blocks [4096,4160) build
//      P[n01][m01][r2]; blocks [4160,4224) build T[m23][n23][r2] --------
__global__ __launch_bounds__(256) void prep0(const float* __restrict__ x,
                                             const float* __restrict__ c0,
                                             const float* __restrict__ c1,
                                             const float* __restrict__ c2,
                                             const float* __restrict__ c3,
                                             bf16_t* __restrict__ xb,
                                             float* __restrict__ Pg,
                                             float* __restrict__ Tg) {
    const int t = threadIdx.x;
    const int b = blockIdx.x;

    if (b < 4096) {                     // ---- cvt_x ----
        int g = b * 256 + t;
        const float4* xv = (const float4*)x;
        float4 a = xv[g * 2];
        float4 c = xv[g * 2 + 1];
        bf16x8 o;
        o[0] = (bf16_t)a.x; o[1] = (bf16_t)a.y; o[2] = (bf16_t)a.z; o[3] = (bf16_t)a.w;
        o[4] = (bf16_t)c.x; o[5] = (bf16_t)c.y; o[6] = (bf16_t)c.z; o[7] = (bf16_t)c.w;
        ((bf16x8*)xb)[g] = o;
        return;
    }

    __shared__ float s0[128];
    __shared__ float s1[2048];

    if (b < 4160) {                     // ---- P[n01][m01][r2] ----
        const int n01 = b - 4096, n0 = n01 >> 3, n1 = n01 & 7;
        if (t < 128) s0[t] = c0[(t >> 4) * 128 + n0 * 16 + (t & 15)];   // [m0][r1]
        for (int i = t; i < 2048; i += 256) {                            // [r1][m1][r2]
            int r1 = i >> 7, m1 = (i >> 4) & 7, r2 = i & 15;
            s1[i] = c1[(r1 * 8 + m1) * 128 + n1 * 16 + r2];
        }
        __syncthreads();
#pragma unroll
        for (int j = 0; j < 4; ++j) {
            int o = j * 256 + t, m01 = o >> 4, r2 = o & 15;
            int m0 = m01 >> 3, m1 = m01 & 7;
            float s = 0.f;
#pragma unroll
            for (int r1 = 0; r1 < 16; ++r1)
                s += s0[m0 * 16 + r1] * s1[r1 * 128 + m1 * 16 + r2];
            Pg[n01 * 1024 + o] = s;
        }
        return;
    }

    {                                   // ---- T[m23][n23][r2] ----
        const int m23 = b - 4160, m2 = m23 >> 3, m3 = m23 & 7;
        if (t < 128) s0[t] = c3[((t >> 3) * 8 + m3) * 8 + (t & 7)];     // [r3][n3]
        for (int i = t; i < 2048; i += 256) {                            // [r2][n2][r3]
            int r2 = i >> 7, n2 = (i >> 4) & 7, r3 = i & 15;
            s1[i] = c2[(r2 * 8 + m2) * 128 + n2 * 16 + r3];
        }
        __syncthreads();
#pragma unroll
        for (int j = 0; j < 4; ++j) {
            int o = j * 256 + t, n23 = o >> 4, r2 = o & 15;
            int n2 = n23 >> 3, n3 = n23 & 7;
            float s = 0.f;
#pragma unroll
            for (int r3 = 0; r3 < 16; ++r3)
                s += s1[r2 * 128 + n2 * 16 + r3] * s0[r3 * 8 + n3];
            Tg[m23 * 1024 + o] = s;
        }
    }
}

// ---- build_w: 256 blocks = (q in [0,4)) x (n01 in [0,64)). (R1 verbatim)
__global__ __launch_bounds__(256) void build_w(const float* __restrict__ Pg,
                                               const float* __restrict__ Tg,
                                               bf16_t* __restrict__ W) {
    const int t = threadIdx.x;
    const int b = blockIdx.x;
    const int n01 = b & 63, q = b >> 6;
    const int cg = t & 15;
    const int mr = t >> 4;
    const float* Pb = Pg + n01 * 1024 + q * 256;   // Pb[ml*16 + r2], uniform

#pragma unroll 1
    for (int ms = 0; ms < 4; ++ms) {
        const int m23 = ms * 16 + mr;
        float Tr[4][16];
#pragma unroll
        for (int jj = 0; jj < 4; ++jj) {
            const float4* tp = (const float4*)(Tg + (m23 * 64 + cg * 4 + jj) * 16);
#pragma unroll
            for (int w = 0; w < 4; ++w) {
                float4 v = tp[w];
                Tr[jj][w * 4 + 0] = v.x;
                Tr[jj][w * 4 + 1] = v.y;
                Tr[jj][w * 4 + 2] = v.z;
                Tr[jj][w * 4 + 3] = v.w;
            }
        }
#pragma unroll 4
        for (int ml = 0; ml < 16; ++ml) {
            float a0 = 0.f, a1 = 0.f, a2 = 0.f, a3 = 0.f;
#pragma unroll
            for (int r2 = 0; r2 < 16; ++r2) {
                float p = Pb[ml * 16 + r2];     // wave-uniform -> SGPR
                a0 += p * Tr[0][r2];
                a1 += p * Tr[1][r2];
                a2 += p * Tr[2][r2];
                a3 += p * Tr[3][r2];
            }
            bf16x4 o;
            o[0] = (bf16_t)a0; o[1] = (bf16_t)a1; o[2] = (bf16_t)a2; o[3] = (bf16_t)a3;
            *(bf16x4*)(W + (size_t)((q * 16 + ml) * 64 + m23) * 4096 + n01 * 64 + cg * 4) = o;
        }
    }
}

// ---- BT GEMM R19 (= R14): C[m,n] = sum_k A[m,k]*B[n,k] + bias[n] -------
// Tile 128(M) x 256(N), BK=64, 512 threads.
__global__ __launch_bounds__(512, 2) void gemm_bt2(const bf16_t* __restrict__ A,
                                                   const bf16_t* __restrict__ B,
                                                   const float* __restrict__ bias,
                                                   float* __restrict__ C) {
    __shared__ bf16_t smem[3][24576];   // per buf: A [0,8192), B [8192,24576)
    const int t = threadIdx.x;
    const int bid = blockIdx.x;
    // Quadrant XCD mapping: XCD x owns bm in [(x&1)*8,+8) x bn in [(x>>1)*4,+4).
    // 32 co-resident blocks/XCD share 8 A-panels (8MB) + 4 B-panels (8MB);
    // per-K-step slab 256KB -> L2-served. Bijective over 256 blocks.
    const int xcd = bid & 7, i = bid >> 3;        // i in [0,32)
    const int bm = (xcd & 1) * 8 + (i & 7);       // [0,16)
    const int bn = (xcd >> 1) * 4 + (i >> 3);     // [0,16)
    const int lane = t & 63, wave = t >> 6;
    const int wm = wave >> 2, wn = wave & 3;

    // staging source (R8 swizzle): srow = t>>3 in [0,64), chunk=(t&7)^(srow&7)
    const int srow = t >> 3;
    const int lc = (t & 7) ^ (srow & 7);
    const bf16_t* Ag = A + (size_t)(bm * 128 + srow) * KD + lc * 8;
    const bf16_t* Bg = B + (size_t)(bn * 256 + srow) * KD + lc * 8;
    const int woff = wave * 512;                  // LDS elems, wave-uniform

    floatx4 acc[4][4];
    floatx4 zero = {0.f, 0.f, 0.f, 0.f};
#pragma unroll
    for (int i2 = 0; i2 < 4; ++i2)
#pragma unroll
        for (int j = 0; j < 4; ++j) acc[i2][j] = zero;

    const int fr = lane & 15;
    const int fc = lane >> 4;

    // ---- prologue: stage tiles 0 and 1 ----
#pragma unroll
    for (int kt = 0; kt < 2; ++kt) {
        bf16_t* bb = &smem[kt][0];
        const size_t ko = (size_t)kt * 64;
#pragma unroll
        for (int c = 0; c < 2; ++c)
            load_lds16(Ag + (size_t)c * 64 * KD + ko, bb + c * 4096 + woff);
#pragma unroll
        for (int c = 0; c < 4; ++c)
            load_lds16(Bg + (size_t)c * 64 * KD + ko, bb + 8192 + c * 4096 + woff);
    }
    asm volatile("s_waitcnt vmcnt(6)\n\ts_barrier" ::: "memory");

    int cur = 0;
#pragma unroll 1
    for (int kt = 0; kt < 64; ++kt) {
        // stage tile kt+2 into buf (cur+2)%3
        if (kt < 62) {
            int nb = cur + 2; if (nb >= 3) nb -= 3;
            bf16_t* bb = &smem[nb][0];
            const size_t ko = (size_t)(kt + 2) * 64;
#pragma unroll
            for (int c = 0; c < 2; ++c)
                load_lds16(Ag + (size_t)c * 64 * KD + ko, bb + c * 4096 + woff);
#pragma unroll
            for (int c = 0; c < 4; ++c)
                load_lds16(Bg + (size_t)c * 64 * KD + ko, bb + 8192 + c * 4096 + woff);
        }

        const bf16_t* Ab = &smem[cur][0];
        const bf16_t* Bb = &smem[cur][8192];
#pragma unroll
        for (int kk = 0; kk < 2; ++kk) {
            const int pA = (fc + kk * 4) ^ (fr & 7);
            bf16x8 af[4], bf[4];
#pragma unroll
            for (int im = 0; im < 4; ++im)
                af[im] = *(const bf16x8*)(Ab + (wm * 64 + im * 16 + fr) * 64 + pA * 8);
#pragma unroll
            for (int in = 0; in < 4; ++in)
                bf[in] = *(const bf16x8*)(Bb + (wn * 64 + in * 16 + fr) * 64 + pA * 8);
            __builtin_amdgcn_s_setprio(1);
#pragma unroll
            for (int im = 0; im < 4; ++im)
#pragma unroll
                for (int in = 0; in < 4; ++in)
                    acc[im][in] = __builtin_amdgcn_mfma_f32_16x16x32_bf16(
                        af[im], bf[in], acc[im][in], 0, 0, 0);
            __builtin_amdgcn_s_setprio(0);
        }

        // Boundary: keep 6 loads (tile kt+2) in flight; drain lgkm so no
        // wave crosses with pending ds_reads of buf[cur] (recycled next
        // iter by DMA from other waves).
        if (kt < 62) {
            asm volatile("s_waitcnt vmcnt(6) lgkmcnt(0)\n\ts_barrier" ::: "memory");
        } else if (kt == 62) {
            asm volatile("s_waitcnt vmcnt(0) lgkmcnt(0)\n\ts_barrier" ::: "memory");
        }
        cur = (cur == 2) ? 0 : cur + 1;
    }

    // epilogue: D[m = (lane>>4)*4 + r][n = lane&15] per 16x16 frag
    const int rl = lane >> 4, cl = lane & 15;
    const size_t rbase = (size_t)bm * 128 + wm * 64;
    const int cbase = bn * 256 + wn * 64;
#pragma unroll
    for (int im = 0; im < 4; ++im) {
#pragma unroll
        for (int in = 0; in < 4; ++in) {
            int col = cbase + in * 16 + cl;
            float bv = bias[col];
#pragma unroll
            for (int r = 0; r < 4; ++r) {
                size_t row = rbase + im * 16 + rl * 4 + r;
                C[row * ND + col] = acc[im][in][r] + bv;
            }
        }
    }
}

extern "C" void kernel_launch(void* const* d_in, const int* in_sizes, int n_in,
                              void* d_out, int out_size, void* d_ws, size_t ws_size,
                              hipStream_t stream) {
    const float* x  = (const float*)d_in[0];
    const float* c0 = (const float*)d_in[1];
    const float* c1 = (const float*)d_in[2];
    const float* c2 = (const float*)d_in[3];
    const float* c3 = (const float*)d_in[4];
    const float* bias = (const float*)d_in[5];
    float* out = (float*)d_out;

    char* ws = (char*)d_ws;
    bf16_t* Xb = (bf16_t*)ws;                 // 16 MiB
    bf16_t* W  = (bf16_t*)(ws + (16u << 20)); // 32 MiB

    // P/T factor tables (512 KB) live at the front of d_out: written by
    // prep0, read by build_w, fully overwritten by gemm_bt2 afterwards.
    float* Pg = (float*)d_out;                // 64*64*16 fp32 = 256 KB
    float* Tg = Pg + 64 * 1024;               // 64*64*16 fp32 = 256 KB

    prep0<<<4224, 256, 0, stream>>>(x, c0, c1, c2, c3, Xb, Pg, Tg);
    build_w<<<256, 256, 0, stream>>>(Pg, Tg, W);
    gemm_bt2<<<256, 512, 0, stream>>>(Xb, W, bias, out);
}